// Round 1
// baseline (244.098 us; speedup 1.0000x reference)
//
#include <hip/hip_runtime.h>
#include <hip/hip_bf16.h>

#define B_ 4
#define T_ 2048
#define D_ 1024
#define N_ 16
#define TCH 32     // timesteps per chunk
#define NCH 64     // number of chunks (TCH*NCH == T_)

typedef __attribute__((ext_vector_type(4))) float f32x4;
typedef __attribute__((ext_vector_type(8))) short short8;
typedef unsigned int u32;
typedef unsigned short u16;

#if defined(__has_builtin)
#if __has_builtin(__builtin_amdgcn_exp2f)
#define EXP2(x) __builtin_amdgcn_exp2f(x)
#else
#define EXP2(x) exp2f(x)
#endif
#else
#define EXP2(x) exp2f(x)
#endif

__device__ __forceinline__ float softplus_f(float v) {
    return v > 20.f ? v : log1pf(__expf(v));
}

// f32 -> bf16 round-to-nearest-even (bit-exact with __float2bfloat16 for our data)
__device__ __forceinline__ u16 f2bf(float f) {
    u32 u = __float_as_uint(f);
    u32 r = (u + 0x7fffu + ((u >> 16) & 1u)) >> 16;
    return (u16)r;
}

// ---------------- convert f32 -> bf16 (vectorized) ----------------
__global__ __launch_bounds__(256) void cvt_f32_bf16(const float* __restrict__ in,
                                                    u16* __restrict__ out, int n4) {
    int i = blockIdx.x * 256 + threadIdx.x;
    if (i >= n4) return;
    float4 v = ((const float4*)in)[i];
    ushort4 o;
    o.x = f2bf(v.x); o.y = f2bf(v.y); o.z = f2bf(v.z); o.w = f2bf(v.w);
    ((ushort4*)out)[i] = o;
}

// ---------------- bf16 GEMM, C[m,n] = sum_k A[m,k]*Bw[n,k]  (+bias, opt softplus)
// m97 structure: 128x128 tile, BK=64, 4 waves (2x2), global_load_lds width 16.
#define BM 128
#define BN 128
#define BK 64

__device__ __forceinline__ void gload_lds16(const void* g, void* l) {
    __builtin_amdgcn_global_load_lds((const __attribute__((address_space(1))) u32*)g,
                                     (__attribute__((address_space(3))) u32*)l, 16, 0, 0);
}

template <int ACT>
__global__ __launch_bounds__(256) void gemm_bt(const u16* __restrict__ A,   // [M,K] bf16
                                               const u16* __restrict__ Bw,  // [N,K] bf16
                                               const float* __restrict__ bias, // [N]
                                               float* __restrict__ C,       // [M,N] f32
                                               int M, int N, int K) {
    __shared__ __align__(16) u16 sA[BM][BK];   // 16 KB
    __shared__ __align__(16) u16 sB[BN][BK];   // 16 KB
    const int tid = threadIdx.x;
    const int wid = tid >> 6;
    const int lane = tid & 63;
    const int m0 = blockIdx.x * BM;
    const int n0 = blockIdx.y * BN;
    const int wm = wid >> 1, wn = wid & 1;  // 2x2 wave grid, each wave 64x64

    const int lrow = lane >> 3;       // 0..7: row within 8-row segment
    const int lcol = (lane & 7) * 8;  // bf16 column (8 elems = 16B per lane)

    f32x4 acc[4][4] = {};

    for (int k0 = 0; k0 < K; k0 += BK) {
        __syncthreads();  // all waves done reading LDS from previous step
        #pragma unroll
        for (int r = 0; r < 4; ++r) {
            const int seg = r * 4 + wid;       // 16 segments of 1KB (8 rows x 128B)
            const int row = seg * 8 + lrow;
            gload_lds16(&A[(size_t)(m0 + row) * K + k0 + lcol],
                        (char*)&sA[0][0] + seg * 1024);
            gload_lds16(&Bw[(size_t)(n0 + row) * K + k0 + lcol],
                        (char*)&sB[0][0] + seg * 1024);
        }
        __syncthreads();  // vmcnt(0) drained by compiler before barrier
        #pragma unroll
        for (int kk = 0; kk < 2; ++kk) {
            short8 af[4], bf[4];
            const int fr = lane & 15;
            const int kof = kk * 32 + (lane >> 4) * 8;
            #pragma unroll
            for (int f = 0; f < 4; ++f) {
                af[f] = *(const short8*)&sA[wm * 64 + f * 16 + fr][kof];
                bf[f] = *(const short8*)&sB[wn * 64 + f * 16 + fr][kof];
            }
            #pragma unroll
            for (int i = 0; i < 4; ++i)
                #pragma unroll
                for (int j = 0; j < 4; ++j)
                    acc[i][j] = __builtin_amdgcn_mfma_f32_16x16x32_bf16(af[i], bf[j],
                                                                        acc[i][j], 0, 0, 0);
        }
    }

    // epilogue: C/D layout col=lane&15, row=(lane>>4)*4+reg (m89-verified)
    const int cl = lane & 15;
    const int rg = (lane >> 4) * 4;
    #pragma unroll
    for (int j = 0; j < 4; ++j) {
        const int col = n0 + wn * 64 + j * 16 + cl;
        const float bv = bias[col];
        #pragma unroll
        for (int i = 0; i < 4; ++i) {
            #pragma unroll
            for (int r = 0; r < 4; ++r) {
                const int rowg = m0 + wm * 64 + i * 16 + rg + r;
                float v = acc[i][j][r] + bv;
                if (ACT) v = softplus_f(v);
                C[(size_t)rowg * N + col] = v;
            }
        }
    }
}

// ---------------- scan phase 1: per-chunk local scan (zero init) ----------------
// thread gid = (c*B + b)*D + d ; states s'[n] (b_param folded out)
__global__ __launch_bounds__(256) void scan_p1(const float* __restrict__ delta,
                                               const float* __restrict__ x,
                                               const float* __restrict__ a_log,
                                               float* __restrict__ S,       // [NCH,B,D,N]
                                               float* __restrict__ dtsum) { // [NCH,B,D]
    const int gid = blockIdx.x * 256 + threadIdx.x;
    const int d = gid & (D_ - 1);
    const int cb = gid >> 10;
    const int b = cb & (B_ - 1);
    const int c = cb >> 2;

    float an2[N_];
    const float4* a4 = (const float4*)&a_log[d * N_];
    #pragma unroll
    for (int q = 0; q < 4; ++q) {
        float4 av = a4[q];
        an2[q * 4 + 0] = (softplus_f(av.x) + 1e-4f) * 1.44269504f;
        an2[q * 4 + 1] = (softplus_f(av.y) + 1e-4f) * 1.44269504f;
        an2[q * 4 + 2] = (softplus_f(av.z) + 1e-4f) * 1.44269504f;
        an2[q * 4 + 3] = (softplus_f(av.w) + 1e-4f) * 1.44269504f;
    }

    float s[N_];
    #pragma unroll
    for (int n = 0; n < N_; ++n) s[n] = 0.f;
    float dts = 0.f;

    const size_t base = ((size_t)b * T_ + (size_t)c * TCH) * D_ + d;
    for (int i = 0; i < TCH; ++i) {
        const float dt = delta[base + (size_t)i * D_];
        const float xv = x[base + (size_t)i * D_];
        const float dtx = dt * xv;
        dts += dt;
        #pragma unroll
        for (int n = 0; n < N_; ++n) {
            const float ab = EXP2(-dt * an2[n]);
            s[n] = fmaf(ab, s[n], dtx);
        }
    }

    float* So = &S[(size_t)gid * N_];
    #pragma unroll
    for (int n = 0; n < N_; ++n) So[n] = s[n];
    dtsum[gid] = dts;
}

// ---------------- scan phase 2: 64-step carry scan across chunks ----------------
// thread gid = (b*D+d)*16+n
__global__ __launch_bounds__(256) void scan_p2(const float* __restrict__ S,
                                               const float* __restrict__ dtsum,
                                               const float* __restrict__ a_log,
                                               float* __restrict__ carry_out) {
    const int gid = blockIdx.x * 256 + threadIdx.x;
    const int n = gid & 15;
    const int d = (gid >> 4) & (D_ - 1);
    const int b = gid >> 14;
    const float an2 = (softplus_f(a_log[d * N_ + n]) + 1e-4f) * 1.44269504f;
    float carry = 0.f;
    for (int c = 0; c < NCH; ++c) {
        const size_t cb = (size_t)c * B_ + b;
        const size_t idx = (cb * D_ + d) * N_ + n;
        carry_out[idx] = carry;                       // carry INTO chunk c
        const float dts = dtsum[cb * D_ + d];
        const float P = EXP2(-dts * an2);             // prod of a_bar over chunk
        carry = fmaf(P, carry, S[idx]);
    }
}

// ---------------- scan phase 3: replay with true carry, emit y (bf16) ----------------
__global__ __launch_bounds__(256) void scan_p3(const float* __restrict__ delta,
                                               const float* __restrict__ x,
                                               const float* __restrict__ a_log,
                                               const float* __restrict__ b_param,
                                               const float* __restrict__ carry_in,
                                               u16* __restrict__ y) {  // [B,T,D] bf16
    const int gid = blockIdx.x * 256 + threadIdx.x;
    const int d = gid & (D_ - 1);
    const int cb = gid >> 10;
    const int b = cb & (B_ - 1);
    const int c = cb >> 2;

    float an2[N_], bp[N_];
    const float4* a4 = (const float4*)&a_log[d * N_];
    const float4* b4 = (const float4*)&b_param[d * N_];
    #pragma unroll
    for (int q = 0; q < 4; ++q) {
        float4 av = a4[q];
        float4 bv = b4[q];
        an2[q * 4 + 0] = (softplus_f(av.x) + 1e-4f) * 1.44269504f;
        an2[q * 4 + 1] = (softplus_f(av.y) + 1e-4f) * 1.44269504f;
        an2[q * 4 + 2] = (softplus_f(av.z) + 1e-4f) * 1.44269504f;
        an2[q * 4 + 3] = (softplus_f(av.w) + 1e-4f) * 1.44269504f;
        bp[q * 4 + 0] = bv.x; bp[q * 4 + 1] = bv.y;
        bp[q * 4 + 2] = bv.z; bp[q * 4 + 3] = bv.w;
    }

    float s[N_];
    const float* ci = &carry_in[(size_t)gid * N_];
    #pragma unroll
    for (int n = 0; n < N_; ++n) s[n] = ci[n];

    const size_t base = ((size_t)b * T_ + (size_t)c * TCH) * D_ + d;
    for (int i = 0; i < TCH; ++i) {
        const float dt = delta[base + (size_t)i * D_];
        const float xv = x[base + (size_t)i * D_];
        const float dtx = dt * xv;
        float acc = 0.f;
        #pragma unroll
        for (int n = 0; n < N_; ++n) {
            const float ab = EXP2(-dt * an2[n]);
            s[n] = fmaf(ab, s[n], dtx);
            acc = fmaf(bp[n], s[n], acc);
        }
        y[base + (size_t)i * D_] = f2bf(acc);
    }
}

// ---------------- launch ----------------
extern "C" void kernel_launch(void* const* d_in, const int* in_sizes, int n_in,
                              void* d_out, int out_size, void* d_ws, size_t ws_size,
                              hipStream_t stream) {
    const float* x      = (const float*)d_in[0];
    const float* Wd     = (const float*)d_in[1];
    const float* bd     = (const float*)d_in[2];
    const float* a_log  = (const float*)d_in[3];
    const float* b_par  = (const float*)d_in[4];
    const float* Wo     = (const float*)d_in[5];
    const float* bo     = (const float*)d_in[6];
    float* out = (float*)d_out;

    char* ws = (char*)d_ws;
    // region A (16 MB): x_bf16 during GEMM1, then carry_in for scan p2/p3
    u16*   xbf     = (u16*)(ws);
    float* carry   = (float*)(ws);
    // region B (16 MB): S during p1/p2, then y_bf16 for p3/GEMM2
    float* S       = (float*)(ws + 16777216);
    u16*   ybf     = (u16*)(ws + 16777216);
    float* delta   = (float*)(ws + 33554432);          // 32 MB
    u16*   wdbf    = (u16*)(ws + 67108864);            // 2 MB
    u16*   wobf    = (u16*)(ws + 69206016);            // 2 MB
    float* dtsum   = (float*)(ws + 71303168);          // 1 MB
    (void)in_sizes; (void)n_in; (void)out_size; (void)ws_size;

    const int M = B_ * T_;  // 8192

    // convert inputs to bf16
    cvt_f32_bf16<<<(M * D_ / 4 + 255) / 256, 256, 0, stream>>>(x, xbf, M * D_ / 4);
    cvt_f32_bf16<<<(D_ * D_ / 4 + 255) / 256, 256, 0, stream>>>(Wd, wdbf, D_ * D_ / 4);
    cvt_f32_bf16<<<(D_ * D_ / 4 + 255) / 256, 256, 0, stream>>>(Wo, wobf, D_ * D_ / 4);

    // delta = softplus(x @ Wd^T + bd)
    gemm_bt<1><<<dim3(M / BM, D_ / BN), 256, 0, stream>>>(xbf, wdbf, bd, delta, M, D_, D_);

    // blocked scan
    scan_p1<<<NCH * B_ * D_ / 256, 256, 0, stream>>>(delta, x, a_log, S, dtsum);
    scan_p2<<<B_ * D_ * N_ / 256, 256, 0, stream>>>(S, dtsum, a_log, carry);
    scan_p3<<<NCH * B_ * D_ / 256, 256, 0, stream>>>(delta, x, a_log, b_par, carry, ybf);

    // out = y @ Wo^T + bo
    gemm_bt<0><<<dim3(M / BM, D_ / BN), 256, 0, stream>>>(ybf, wobf, bo, out, M, D_, D_);
}

// Round 3
// 220.977 us; speedup vs baseline: 1.1046x; 1.1046x over previous
//
#include <hip/hip_runtime.h>
#include <hip/hip_bf16.h>

#define B_ 4
#define T_ 2048
#define D_ 1024
#define N_ 16
#define TCH 32     // timesteps per chunk
#define NCH 64     // number of chunks (TCH*NCH == T_)

typedef __attribute__((ext_vector_type(4))) float f32x4;
typedef __attribute__((ext_vector_type(8))) short short8;
typedef unsigned int u32;
typedef unsigned short u16;

#if defined(__has_builtin)
#if __has_builtin(__builtin_amdgcn_exp2f)
#define EXP2(x) __builtin_amdgcn_exp2f(x)
#else
#define EXP2(x) exp2f(x)
#endif
#else
#define EXP2(x) exp2f(x)
#endif

__device__ __forceinline__ float softplus_f(float v) {
    return v > 20.f ? v : log1pf(__expf(v));
}

// f32 -> bf16 round-to-nearest-even
__device__ __forceinline__ u16 f2bf(float f) {
    u32 u = __float_as_uint(f);
    u32 r = (u + 0x7fffu + ((u >> 16) & 1u)) >> 16;
    return (u16)r;
}

// ---------------- convert f32 -> bf16 (vectorized) ----------------
__global__ __launch_bounds__(256) void cvt_f32_bf16(const float* __restrict__ in,
                                                    u16* __restrict__ out, int n4) {
    int i = blockIdx.x * 256 + threadIdx.x;
    if (i >= n4) return;
    float4 v = ((const float4*)in)[i];
    ushort4 o;
    o.x = f2bf(v.x); o.y = f2bf(v.y); o.z = f2bf(v.z); o.w = f2bf(v.w);
    ((ushort4*)out)[i] = o;
}

// ---------------- bf16 GEMM, C[m,n] = sum_k A[m,k]*Bw[n,k]  (+bias, opt softplus)
// 128x128 tile, BK=64, 4 waves (2x2), double-buffered LDS, 2-phase pipeline,
// XOR bank-swizzle via pre-swizzled global source (rule #21: linear dest +
// inverse-swizzled source + swizzled read).
#define BM 128
#define BN 128
#define BK 64

__device__ __forceinline__ void gload_lds16(const void* g, void* l) {
    __builtin_amdgcn_global_load_lds((const __attribute__((address_space(1))) u32*)g,
                                     (__attribute__((address_space(3))) u32*)l, 16, 0, 0);
}

template <int ACT>
__global__ __launch_bounds__(256, 2) void gemm_bt(const u16* __restrict__ A,   // [M,K] bf16
                                                  const u16* __restrict__ Bw,  // [N,K] bf16
                                                  const float* __restrict__ bias, // [N]
                                                  float* __restrict__ C,       // [M,N] f32
                                                  int M, int N, int K) {
    __shared__ __align__(16) u16 sA[2][BM * BK];   // 2 x 16 KB
    __shared__ __align__(16) u16 sB[2][BN * BK];   // 2 x 16 KB
    const int tid = threadIdx.x;
    const int wid = tid >> 6;
    const int lane = tid & 63;
    const int m0 = blockIdx.x * BM;
    const int n0 = blockIdx.y * BN;
    const int wm = wid >> 1, wn = wid & 1;  // 2x2 wave grid, each wave 64x64

    // staging geometry: 16 segments of 8 rows x 128B; wave handles segs wid, wid+4, ...
    const int lrow = lane >> 3;   // 0..7 row within segment
    const int slot = lane & 7;    // 16B slot within row
    const int ksw = (slot ^ lrow) << 3;  // inverse-swizzled k offset (u16 units)

    size_t aRow[4], bRow[4];
    int segOf[4];
    #pragma unroll
    for (int r = 0; r < 4; ++r) {
        const int seg = r * 4 + wid;
        const int row = seg * 8 + lrow;
        aRow[r] = (size_t)(m0 + row) * K + ksw;
        bRow[r] = (size_t)(n0 + row) * K + ksw;
        segOf[r] = seg * 1024;  // LDS byte offset (wave-uniform)
    }

    f32x4 acc[4][4] = {};

    const int nt = K / BK;
    int cur = 0;

    // prologue: stage tile 0
    #pragma unroll
    for (int r = 0; r < 4; ++r) {
        gload_lds16(A + aRow[r], (char*)sA[0] + segOf[r]);
        gload_lds16(Bw + bRow[r], (char*)sB[0] + segOf[r]);
    }
    __syncthreads();

    const int fr = lane & 15;
    const int g = lane >> 4;
    const int xorv = (fr & 7) << 4;

    for (int t = 0; t < nt; ++t) {
        // issue next-tile staging FIRST (latency hides under this tile's compute)
        if (t + 1 < nt) {
            const int k0 = (t + 1) * BK;
            #pragma unroll
            for (int r = 0; r < 4; ++r) {
                gload_lds16(A + aRow[r] + k0, (char*)sA[cur ^ 1] + segOf[r]);
                gload_lds16(Bw + bRow[r] + k0, (char*)sB[cur ^ 1] + segOf[r]);
            }
        }
        // compute current tile
        #pragma unroll
        for (int kk = 0; kk < 2; ++kk) {
            const int ksb = (kk * 64 + g * 16) ^ xorv;  // swizzled k-byte
            short8 af[4], bf[4];
            #pragma unroll
            for (int f = 0; f < 4; ++f) {
                af[f] = *(const short8*)((const char*)sA[cur] + (wm * 64 + f * 16 + fr) * 128 + ksb);
                bf[f] = *(const short8*)((const char*)sB[cur] + (wn * 64 + f * 16 + fr) * 128 + ksb);
            }
            #pragma unroll
            for (int i = 0; i < 4; ++i)
                #pragma unroll
                for (int j = 0; j < 4; ++j)
                    acc[i][j] = __builtin_amdgcn_mfma_f32_16x16x32_bf16(af[i], bf[j],
                                                                        acc[i][j], 0, 0, 0);
        }
        __syncthreads();  // drains vmcnt(0): next tile staged; this tile's LDS free
        cur ^= 1;
    }

    // epilogue: C/D layout col=lane&15, row=(lane>>4)*4+reg (m89-verified)
    const int cl = lane & 15;
    const int rg = (lane >> 4) * 4;
    #pragma unroll
    for (int j = 0; j < 4; ++j) {
        const int col = n0 + wn * 64 + j * 16 + cl;
        const float bv = bias[col];
        #pragma unroll
        for (int i = 0; i < 4; ++i) {
            #pragma unroll
            for (int r = 0; r < 4; ++r) {
                const int rowg = m0 + wm * 64 + i * 16 + rg + r;
                float v = acc[i][j][r] + bv;
                if (ACT) v = softplus_f(v);
                C[(size_t)rowg * N + col] = v;
            }
        }
    }
}

// ---------------- scan phase 1: per-chunk local scan (zero init) ----------------
__global__ __launch_bounds__(256) void scan_p1(const float* __restrict__ delta,
                                               const float* __restrict__ x,
                                               const float* __restrict__ a_log,
                                               float* __restrict__ S,       // [NCH,B,D,N]
                                               float* __restrict__ dtsum) { // [NCH,B,D]
    const int gid = blockIdx.x * 256 + threadIdx.x;
    const int d = gid & (D_ - 1);
    const int cb = gid >> 10;
    const int b = cb & (B_ - 1);
    const int c = cb >> 2;

    float an2[N_];
    const float4* a4 = (const float4*)&a_log[d * N_];
    #pragma unroll
    for (int q = 0; q < 4; ++q) {
        float4 av = a4[q];
        an2[q * 4 + 0] = (softplus_f(av.x) + 1e-4f) * 1.44269504f;
        an2[q * 4 + 1] = (softplus_f(av.y) + 1e-4f) * 1.44269504f;
        an2[q * 4 + 2] = (softplus_f(av.z) + 1e-4f) * 1.44269504f;
        an2[q * 4 + 3] = (softplus_f(av.w) + 1e-4f) * 1.44269504f;
    }

    float s[N_];
    #pragma unroll
    for (int n = 0; n < N_; ++n) s[n] = 0.f;
    float dts = 0.f;

    const size_t base = ((size_t)b * T_ + (size_t)c * TCH) * D_ + d;
    for (int i = 0; i < TCH; ++i) {
        const float dt = delta[base + (size_t)i * D_];
        const float xv = x[base + (size_t)i * D_];
        const float dtx = dt * xv;
        dts += dt;
        #pragma unroll
        for (int n = 0; n < N_; ++n) {
            const float ab = EXP2(-dt * an2[n]);
            s[n] = fmaf(ab, s[n], dtx);
        }
    }

    float* So = &S[(size_t)gid * N_];
    #pragma unroll
    for (int n = 0; n < N_; ++n) So[n] = s[n];
    dtsum[gid] = dts;
}

// ---------------- scan phase 2: 64-step carry scan across chunks ----------------
__global__ __launch_bounds__(256) void scan_p2(const float* __restrict__ S,
                                               const float* __restrict__ dtsum,
                                               const float* __restrict__ a_log,
                                               float* __restrict__ carry_out) {
    const int gid = blockIdx.x * 256 + threadIdx.x;
    const int n = gid & 15;
    const int d = (gid >> 4) & (D_ - 1);
    const int b = gid >> 14;
    const float an2 = (softplus_f(a_log[d * N_ + n]) + 1e-4f) * 1.44269504f;
    float carry = 0.f;
    for (int c = 0; c < NCH; ++c) {
        const size_t cb = (size_t)c * B_ + b;
        const size_t idx = (cb * D_ + d) * N_ + n;
        carry_out[idx] = carry;                       // carry INTO chunk c
        const float dts = dtsum[cb * D_ + d];
        const float P = EXP2(-dts * an2);             // prod of a_bar over chunk
        carry = fmaf(P, carry, S[idx]);
    }
}

// ---------------- scan phase 3: replay with true carry, emit y (bf16) ----------------
__global__ __launch_bounds__(256) void scan_p3(const float* __restrict__ delta,
                                               const float* __restrict__ x,
                                               const float* __restrict__ a_log,
                                               const float* __restrict__ b_param,
                                               const float* __restrict__ carry_in,
                                               u16* __restrict__ y) {  // [B,T,D] bf16
    const int gid = blockIdx.x * 256 + threadIdx.x;
    const int d = gid & (D_ - 1);
    const int cb = gid >> 10;
    const int b = cb & (B_ - 1);
    const int c = cb >> 2;

    float an2[N_], bp[N_];
    const float4* a4 = (const float4*)&a_log[d * N_];
    const float4* b4 = (const float4*)&b_param[d * N_];
    #pragma unroll
    for (int q = 0; q < 4; ++q) {
        float4 av = a4[q];
        float4 bv = b4[q];
        an2[q * 4 + 0] = (softplus_f(av.x) + 1e-4f) * 1.44269504f;
        an2[q * 4 + 1] = (softplus_f(av.y) + 1e-4f) * 1.44269504f;
        an2[q * 4 + 2] = (softplus_f(av.z) + 1e-4f) * 1.44269504f;
        an2[q * 4 + 3] = (softplus_f(av.w) + 1e-4f) * 1.44269504f;
        bp[q * 4 + 0] = bv.x; bp[q * 4 + 1] = bv.y;
        bp[q * 4 + 2] = bv.z; bp[q * 4 + 3] = bv.w;
    }

    float s[N_];
    const float* ci = &carry_in[(size_t)gid * N_];
    #pragma unroll
    for (int n = 0; n < N_; ++n) s[n] = ci[n];

    const size_t base = ((size_t)b * T_ + (size_t)c * TCH) * D_ + d;
    for (int i = 0; i < TCH; ++i) {
        const float dt = delta[base + (size_t)i * D_];
        const float xv = x[base + (size_t)i * D_];
        const float dtx = dt * xv;
        float acc = 0.f;
        #pragma unroll
        for (int n = 0; n < N_; ++n) {
            const float ab = EXP2(-dt * an2[n]);
            s[n] = fmaf(ab, s[n], dtx);
            acc = fmaf(bp[n], s[n], acc);
        }
        y[base + (size_t)i * D_] = f2bf(acc);
    }
}

// ---------------- launch ----------------
extern "C" void kernel_launch(void* const* d_in, const int* in_sizes, int n_in,
                              void* d_out, int out_size, void* d_ws, size_t ws_size,
                              hipStream_t stream) {
    const float* x      = (const float*)d_in[0];
    const float* Wd     = (const float*)d_in[1];
    const float* bd     = (const float*)d_in[2];
    const float* a_log  = (const float*)d_in[3];
    const float* b_par  = (const float*)d_in[4];
    const float* Wo     = (const float*)d_in[5];
    const float* bo     = (const float*)d_in[6];
    float* out = (float*)d_out;

    char* ws = (char*)d_ws;
    // region A (16 MB): x_bf16 during GEMM1, then carry_in for scan p2/p3
    u16*   xbf     = (u16*)(ws);
    float* carry   = (float*)(ws);
    // region B (16 MB): S during p1/p2, then y_bf16 for p3/GEMM2
    float* S       = (float*)(ws + 16777216);
    u16*   ybf     = (u16*)(ws + 16777216);
    float* delta   = (float*)(ws + 33554432);          // 32 MB
    u16*   wdbf    = (u16*)(ws + 67108864);            // 2 MB
    u16*   wobf    = (u16*)(ws + 69206016);            // 2 MB
    float* dtsum   = (float*)(ws + 71303168);          // 1 MB
    (void)in_sizes; (void)n_in; (void)out_size; (void)ws_size;

    const int M = B_ * T_;  // 8192

    // convert inputs to bf16
    cvt_f32_bf16<<<(M * D_ / 4 + 255) / 256, 256, 0, stream>>>(x, xbf, M * D_ / 4);
    cvt_f32_bf16<<<(D_ * D_ / 4 + 255) / 256, 256, 0, stream>>>(Wd, wdbf, D_ * D_ / 4);
    cvt_f32_bf16<<<(D_ * D_ / 4 + 255) / 256, 256, 0, stream>>>(Wo, wobf, D_ * D_ / 4);

    // delta = softplus(x @ Wd^T + bd)
    gemm_bt<1><<<dim3(M / BM, D_ / BN), 256, 0, stream>>>(xbf, wdbf, bd, delta, M, D_, D_);

    // blocked scan
    scan_p1<<<NCH * B_ * D_ / 256, 256, 0, stream>>>(delta, x, a_log, S, dtsum);
    scan_p2<<<B_ * D_ * N_ / 256, 256, 0, stream>>>(S, dtsum, a_log, carry);
    scan_p3<<<NCH * B_ * D_ / 256, 256, 0, stream>>>(delta, x, a_log, b_par, carry, ybf);

    // out = y @ Wo^T + bo
    gemm_bt<0><<<dim3(M / BM, D_ / BN), 256, 0, stream>>>(ybf, wobf, bo, out, M, D_, D_);
}